// Round 2
// baseline (576.521 us; speedup 1.0000x reference)
//
#include <hip/hip_runtime.h>
#include <hip/hip_bf16.h>
#include <cstdint>
#include <cstddef>

// Problem constants (fixed by the reference setup)
#define NE 8
#define NT 16384
#define ND 2048
#define NH 1024

typedef __bf16 bf16;
typedef __bf16 bf16x8 __attribute__((ext_vector_type(8)));
typedef float f32x4 __attribute__((ext_vector_type(4)));

// Address-space casts for global_load_lds.
#define AS1(p) ((__attribute__((address_space(1))) void*)(uintptr_t)(p))
#define AS3(p) ((__attribute__((address_space(3))) void*)(uint32_t)(uintptr_t)(p))
// 16B-wide async global->LDS. HW writes wave-uniform base + lane*16: per-wave
// LDS destinations are exactly contiguous (t*16B), swizzle applied on the
// GLOBAL source address instead (both-sides-or-neither rule).
#define GLDS16(g, l) __builtin_amdgcn_global_load_lds(AS1(g), AS3(l), 16, 0, 0)

// Counted waits / raw barrier. "memory" clobber pins all LDS/global ops on the
// correct side; sched_barrier(0) additionally pins register-only MFMA (rule 18).
#define WAIT_VM(n) asm volatile("s_waitcnt vmcnt(" #n ")" ::: "memory")
#define WAIT_LGKM0() asm volatile("s_waitcnt lgkmcnt(0)" ::: "memory")
#define BAR() asm volatile("s_barrier" ::: "memory")
#define SCHED_FENCE() __builtin_amdgcn_sched_barrier(0)

// LDS XOR swizzle (0-conflict, measured): physical 16B slot p of row r holds
// logical col-block p ^ ((r>>1)&3). Staged via pre-swizzled global column,
// read back with kqs = kq ^ ((l16>>1)&3) (lane-invariant term).

__device__ __forceinline__ int expert_of_row(const int* __restrict__ counts, int row0) {
  int e = 0, cum = 0;
#pragma unroll
  for (int i = 0; i < NE; ++i) {
    if (row0 >= cum) e = i;
    cum += counts[i];
  }
  return e;
}

// ---------------- f32 -> bf16 conversion (memory-bound, 8 elem/thread) -------
__global__ void cvt_kernel(const float* __restrict__ src, bf16* __restrict__ dst, int n8) {
  int i = blockIdx.x * blockDim.x + threadIdx.x;
  if (i >= n8) return;
  const f32x4* s = (const f32x4*)src + (size_t)i * 2;
  f32x4 a = s[0];
  f32x4 b = s[1];
  bf16x8 o;
  o[0] = (bf16)a[0]; o[1] = (bf16)a[1]; o[2] = (bf16)a[2]; o[3] = (bf16)a[3];
  o[4] = (bf16)b[0]; o[5] = (bf16)b[1]; o[6] = (bf16)b[2]; o[7] = (bf16)b[3];
  *((bf16x8*)dst + i) = o;
}

// ---------------- GEMM1: h = silu(x @ w1^T) * (x @ w3^T), bf16 out -----------
// Tile: BM=256, BN=128(dual w1+w3), BK=32. 512 thr = 8 waves (2 row x 4 col);
// wave owns 128x32 of BOTH h1,h3. 4-deep pipelined LDS (128 KiB), each K-tile
// split into 2 barrier-fenced phases (m201 rhythm): reads+stage | bar | MFMA |
// bar. Counted vmcnt before phase-B barrier keeps 2 tiles in flight.
__global__ __launch_bounds__(512, 2) void gemm1_kernel(
    const bf16* __restrict__ X, const bf16* __restrict__ W1,
    const bf16* __restrict__ W3, const int* __restrict__ counts,
    bf16* __restrict__ Hb) {
  const int cb = blockIdx.x;   // NH/128 = 8
  const int rb = blockIdx.y;   // NT/256 = 64
  const int t = threadIdx.x;
  const int lane = t & 63;
  const int wave = t >> 6;     // 0..7
  const int wr = wave >> 2;    // 0..1 : 128 rows each
  const int wc = wave & 3;     // 0..3 : 32 cols each
  const int l16 = lane & 15;
  const int kq = lane >> 4;
  const int kqs = kq ^ ((l16 >> 1) & 3);

  const int row0 = rb * 256;
  const int e = expert_of_row(counts, row0);

  const bf16* Xe  = X  + (size_t)row0 * ND;
  const bf16* W1e = W1 + (size_t)e * NH * ND + (size_t)cb * 128 * ND;
  const bf16* W3e = W3 + (size_t)e * NH * ND + (size_t)cb * 128 * ND;

  __shared__ __align__(16) bf16 lds[4 * 16384];   // 128 KiB

  const int srow = t >> 2;                             // 0..127
  const int scol = (((t & 3) ^ ((t >> 3) & 3)) * 8);   // swizzled col-block

  const bf16* gA  = Xe  + (size_t)srow * ND + scol;
  const bf16* gB1 = W1e + (size_t)srow * ND + scol;
  const bf16* gB3 = W3e + (size_t)srow * ND + scol;

  const int a_base  = (wr * 128 + l16) * 32 + kqs * 8;
  const int b1_base = 8192  + (wc * 32 + l16) * 32 + kqs * 8;
  const int b3_base = 12288 + (wc * 32 + l16) * 32 + kqs * 8;

  f32x4 acc1[8][2] = {};
  f32x4 acc3[8][2] = {};

  const int NK = ND / 32;   // 64

  // Prologue: stage K-tiles 0,1,2 (12 loads/thread in flight), sync on tile 0.
#pragma unroll
  for (int p = 0; p < 3; ++p) {
    bf16* buf = lds + p * 16384;
    const int ko = p * 32;
    GLDS16(gA  + ko,                    buf + t * 8);
    GLDS16(gA  + (size_t)128 * ND + ko, buf + 4096 + t * 8);
    GLDS16(gB1 + ko,                    buf + 8192 + t * 8);
    GLDS16(gB3 + ko,                    buf + 12288 + t * 8);
  }
  WAIT_VM(8);
  BAR();

  for (int kt = 0; kt < NK; ++kt) {
    bf16* buf = lds + (kt & 3) * 16384;
    bf16* nb  = lds + ((kt + 3) & 3) * 16384;   // == (kt-1)&3: consumed last iter
    const bool st = (kt + 3 < NK);
    const int ko = (kt + 3) * 32;

    // ---- phase A: 8 ds_read + A-staging | bar | 16 MFMA | bar ----
    bf16x8 b1[2], b3[2], a0[4];
#pragma unroll
    for (int j = 0; j < 2; ++j) {
      b1[j] = *(const bf16x8*)(buf + b1_base + j * 512);
      b3[j] = *(const bf16x8*)(buf + b3_base + j * 512);
    }
#pragma unroll
    for (int i = 0; i < 4; ++i)
      a0[i] = *(const bf16x8*)(buf + a_base + i * 512);
    if (st) {
      GLDS16(gA + ko,                    nb + t * 8);
      GLDS16(gA + (size_t)128 * ND + ko, nb + 4096 + t * 8);
    }
    BAR();
    WAIT_LGKM0();
    SCHED_FENCE();
    __builtin_amdgcn_s_setprio(1);
#pragma unroll
    for (int i = 0; i < 4; ++i)
#pragma unroll
      for (int j = 0; j < 2; ++j) {
        acc1[i][j] = __builtin_amdgcn_mfma_f32_16x16x32_bf16(a0[i], b1[j], acc1[i][j], 0, 0, 0);
        acc3[i][j] = __builtin_amdgcn_mfma_f32_16x16x32_bf16(a0[i], b3[j], acc3[i][j], 0, 0, 0);
      }
    __builtin_amdgcn_s_setprio(0);
    SCHED_FENCE();
    BAR();

    // ---- phase B: 4 ds_read + B-staging + counted vmcnt | bar | 16 MFMA | bar
    bf16x8 a1[4];
#pragma unroll
    for (int i = 0; i < 4; ++i)
      a1[i] = *(const bf16x8*)(buf + a_base + (4 + i) * 512);
    if (st) {
      GLDS16(gB1 + ko, nb + 8192 + t * 8);
      GLDS16(gB3 + ko, nb + 12288 + t * 8);
    }
    // Tile kt+1 must be fully landed before every wave's next phase-A reads;
    // tiles kt+2, kt+3 stay in flight (never drain to 0 mid-loop).
    if (kt + 3 < NK)      WAIT_VM(8);
    else if (kt + 2 < NK) WAIT_VM(4);
    else if (kt + 1 < NK) WAIT_VM(0);
    BAR();
    WAIT_LGKM0();
    SCHED_FENCE();
    __builtin_amdgcn_s_setprio(1);
#pragma unroll
    for (int i = 0; i < 4; ++i)
#pragma unroll
      for (int j = 0; j < 2; ++j) {
        acc1[4 + i][j] = __builtin_amdgcn_mfma_f32_16x16x32_bf16(a1[i], b1[j], acc1[4 + i][j], 0, 0, 0);
        acc3[4 + i][j] = __builtin_amdgcn_mfma_f32_16x16x32_bf16(a1[i], b3[j], acc3[4 + i][j], 0, 0, 0);
      }
    __builtin_amdgcn_s_setprio(0);
    SCHED_FENCE();
    BAR();
  }

  // Epilogue: C/D layout col=lane&15, row=(lane>>4)*4+reg. silu(a1)*a3 -> bf16.
  const int rbase = row0 + wr * 128 + kq * 4;
  const int cbase = cb * 128 + wc * 32 + l16;
#pragma unroll
  for (int i = 0; i < 8; ++i)
#pragma unroll
    for (int j = 0; j < 2; ++j) {
      const int col = cbase + j * 16;
#pragma unroll
      for (int r = 0; r < 4; ++r) {
        const int row = rbase + i * 16 + r;
        const float v1 = acc1[i][j][r];
        const float v3 = acc3[i][j][r];
        const float hv = (v1 / (1.0f + __expf(-v1))) * v3;
        Hb[(size_t)row * NH + col] = (bf16)hv;
      }
    }
}

// ---------------- GEMM2: out = h @ w2^T, f32 out ------------------------------
// Tile: BM=256, BN=256, BK=32. 8 waves (2x4); wave owns 128x64. Same 4-deep
// 2-phase pipeline as gemm1.
__global__ __launch_bounds__(512, 2) void gemm2_kernel(
    const bf16* __restrict__ Hb, const bf16* __restrict__ W2,
    const int* __restrict__ counts, float* __restrict__ Out) {
  const int cb = blockIdx.x;   // ND/256 = 8
  const int rb = blockIdx.y;   // NT/256 = 64
  const int t = threadIdx.x;
  const int lane = t & 63;
  const int wave = t >> 6;
  const int wr = wave >> 2;    // 0..1 : 128 rows
  const int wc = wave & 3;     // 0..3 : 64 cols
  const int l16 = lane & 15;
  const int kq = lane >> 4;
  const int kqs = kq ^ ((l16 >> 1) & 3);

  const int row0 = rb * 256;
  const int e = expert_of_row(counts, row0);

  const bf16* He  = Hb + (size_t)row0 * NH;
  const bf16* W2e = W2 + (size_t)e * ND * NH + (size_t)cb * 256 * NH;

  __shared__ __align__(16) bf16 lds[4 * 16384];   // 128 KiB

  const int srow = t >> 2;
  const int scol = (((t & 3) ^ ((t >> 3) & 3)) * 8);

  const bf16* gA = He  + (size_t)srow * NH + scol;
  const bf16* gB = W2e + (size_t)srow * NH + scol;

  const int a_base = (wr * 128 + l16) * 32 + kqs * 8;
  const int b_base = 8192 + (wc * 64 + l16) * 32 + kqs * 8;

  f32x4 acc[8][4] = {};

  const int NK = NH / 32;   // 32

#pragma unroll
  for (int p = 0; p < 3; ++p) {
    bf16* buf = lds + p * 16384;
    const int ko = p * 32;
    GLDS16(gA + ko,                    buf + t * 8);
    GLDS16(gA + (size_t)128 * NH + ko, buf + 4096 + t * 8);
    GLDS16(gB + ko,                    buf + 8192 + t * 8);
    GLDS16(gB + (size_t)128 * NH + ko, buf + 12288 + t * 8);
  }
  WAIT_VM(8);
  BAR();

  for (int kt = 0; kt < NK; ++kt) {
    bf16* buf = lds + (kt & 3) * 16384;
    bf16* nb  = lds + ((kt + 3) & 3) * 16384;
    const bool st = (kt + 3 < NK);
    const int ko = (kt + 3) * 32;

    // ---- phase A ----
    bf16x8 b[4], a0[4];
#pragma unroll
    for (int j = 0; j < 4; ++j)
      b[j] = *(const bf16x8*)(buf + b_base + j * 512);
#pragma unroll
    for (int i = 0; i < 4; ++i)
      a0[i] = *(const bf16x8*)(buf + a_base + i * 512);
    if (st) {
      GLDS16(gA + ko,                    nb + t * 8);
      GLDS16(gA + (size_t)128 * NH + ko, nb + 4096 + t * 8);
    }
    BAR();
    WAIT_LGKM0();
    SCHED_FENCE();
    __builtin_amdgcn_s_setprio(1);
#pragma unroll
    for (int i = 0; i < 4; ++i)
#pragma unroll
      for (int j = 0; j < 4; ++j)
        acc[i][j] = __builtin_amdgcn_mfma_f32_16x16x32_bf16(a0[i], b[j], acc[i][j], 0, 0, 0);
    __builtin_amdgcn_s_setprio(0);
    SCHED_FENCE();
    BAR();

    // ---- phase B ----
    bf16x8 a1[4];
#pragma unroll
    for (int i = 0; i < 4; ++i)
      a1[i] = *(const bf16x8*)(buf + a_base + (4 + i) * 512);
    if (st) {
      GLDS16(gB + ko,                    nb + 8192 + t * 8);
      GLDS16(gB + (size_t)128 * NH + ko, nb + 12288 + t * 8);
    }
    if (kt + 3 < NK)      WAIT_VM(8);
    else if (kt + 2 < NK) WAIT_VM(4);
    else if (kt + 1 < NK) WAIT_VM(0);
    BAR();
    WAIT_LGKM0();
    SCHED_FENCE();
    __builtin_amdgcn_s_setprio(1);
#pragma unroll
    for (int i = 0; i < 4; ++i)
#pragma unroll
      for (int j = 0; j < 4; ++j)
        acc[4 + i][j] = __builtin_amdgcn_mfma_f32_16x16x32_bf16(a1[i], b[j], acc[4 + i][j], 0, 0, 0);
    __builtin_amdgcn_s_setprio(0);
    SCHED_FENCE();
    BAR();
  }

  const int rbase = row0 + wr * 128 + kq * 4;
  const int cbase = cb * 256 + wc * 64 + l16;
#pragma unroll
  for (int i = 0; i < 8; ++i)
#pragma unroll
    for (int j = 0; j < 4; ++j) {
      const int col = cbase + j * 16;
#pragma unroll
      for (int r = 0; r < 4; ++r) {
        const int row = rbase + i * 16 + r;
        Out[(size_t)row * ND + col] = acc[i][j][r];
      }
    }
}

// -----------------------------------------------------------------------------
extern "C" void kernel_launch(void* const* d_in, const int* in_sizes, int n_in,
                              void* d_out, int out_size, void* d_ws, size_t ws_size,
                              hipStream_t stream) {
  const float* x     = (const float*)d_in[0];
  const int* counts  = (const int*)d_in[1];
  const float* w1    = (const float*)d_in[2];
  const float* w2    = (const float*)d_in[3];
  const float* w3    = (const float*)d_in[4];
  float* out = (float*)d_out;

  char* ws = (char*)d_ws;
  const size_t xN = (size_t)NT * ND;       // 33.5M elems
  const size_t wN = (size_t)NE * NH * ND;  // 16.8M elems per weight
  bf16* xb  = (bf16*)ws;                                  //  64 MiB
  bf16* w1b = (bf16*)(ws + xN * 2);                       // +32 MiB
  bf16* w3b = (bf16*)(ws + xN * 2 + wN * 2);              // +32 MiB
  bf16* w2b = (bf16*)(ws + xN * 2 + 2 * wN * 2);          // +32 MiB
  bf16* hb  = (bf16*)(ws + xN * 2 + 3 * wN * 2);          // +32 MiB (h: T x H bf16)

  { int n8 = (int)(xN / 8); cvt_kernel<<<dim3((n8 + 255) / 256), dim3(256), 0, stream>>>(x, xb, n8); }
  { int n8 = (int)(wN / 8); cvt_kernel<<<dim3((n8 + 255) / 256), dim3(256), 0, stream>>>(w1, w1b, n8); }
  { int n8 = (int)(wN / 8); cvt_kernel<<<dim3((n8 + 255) / 256), dim3(256), 0, stream>>>(w3, w3b, n8); }
  { int n8 = (int)(wN / 8); cvt_kernel<<<dim3((n8 + 255) / 256), dim3(256), 0, stream>>>(w2, w2b, n8); }

  gemm1_kernel<<<dim3(NH / 128, NT / 256), dim3(512), 0, stream>>>(xb, w1b, w3b, counts, hb);
  gemm2_kernel<<<dim3(ND / 256, NT / 256), dim3(512), 0, stream>>>(hb, w2b, counts, out);
}

// Round 3
// 562.330 us; speedup vs baseline: 1.0252x; 1.0252x over previous
//
#include <hip/hip_runtime.h>
#include <hip/hip_bf16.h>
#include <cstdint>
#include <cstddef>

// Problem constants (fixed by the reference setup)
#define NE 8
#define NT 16384
#define ND 2048
#define NH 1024

typedef __bf16 bf16;
typedef __bf16 bf16x8 __attribute__((ext_vector_type(8)));
typedef float f32x4 __attribute__((ext_vector_type(4)));

// Address-space casts for global_load_lds.
#define AS1(p) ((__attribute__((address_space(1))) void*)(uintptr_t)(p))
#define AS3(p) ((__attribute__((address_space(3))) void*)(uint32_t)(uintptr_t)(p))
// 16B-wide async global->LDS. HW writes wave-uniform base + lane*16: per-wave
// LDS destinations are exactly contiguous (t*16B); swizzle applied on the
// GLOBAL source address (both-sides-or-neither rule).
#define GLDS16(g, l) __builtin_amdgcn_global_load_lds(AS1(g), AS3(l), 16, 0, 0)

// Counted wait / raw barrier. NO sched_barrier, NO forced lgkm(0): ds_reads
// are plain C++ loads, the compiler emits fine-grained lgkmcnt itself (m141:
// pinning the order regresses). "memory" clobber only pins memory-op ORDER.
#define WAIT_VM(n) asm volatile("s_waitcnt vmcnt(" #n ")" ::: "memory")
#define BAR() asm volatile("s_barrier" ::: "memory")

// LDS swizzle for BK=64 (128-B rows = exact 32-bank wrap): 8 slots of 16B per
// row; physical slot = logical slot ^ (row & 7). Stage thread t writes linear
// LDS (row=t>>3, phys=t&7) from global col-block (t&7)^((t>>3)&7); reads use
// slot_log = ks*4+kq, phys = slot_log ^ (l16&7). One ds_read_b128: 8 lanes on
// each of 8 bank-quads -> uniform, conflict-free.

__device__ __forceinline__ int expert_of_row(const int* __restrict__ counts, int row0) {
  int e = 0, cum = 0;
#pragma unroll
  for (int i = 0; i < NE; ++i) {
    if (row0 >= cum) e = i;
    cum += counts[i];
  }
  return e;
}

// ---------------- f32 -> bf16 conversion (memory-bound, 8 elem/thread) -------
__global__ void cvt_kernel(const float* __restrict__ src, bf16* __restrict__ dst, int n8) {
  int i = blockIdx.x * blockDim.x + threadIdx.x;
  if (i >= n8) return;
  const f32x4* s = (const f32x4*)src + (size_t)i * 2;
  f32x4 a = s[0];
  f32x4 b = s[1];
  bf16x8 o;
  o[0] = (bf16)a[0]; o[1] = (bf16)a[1]; o[2] = (bf16)a[2]; o[3] = (bf16)a[3];
  o[4] = (bf16)b[0]; o[5] = (bf16)b[1]; o[6] = (bf16)b[2]; o[7] = (bf16)b[3];
  *((bf16x8*)dst + i) = o;
}

// ---------------- GEMM1: h = silu(x @ w1^T) * (x @ w3^T), bf16 out -----------
// BM=256, BN=128(dual w1+w3), BK=64. 8 waves (2 row x 4 col); wave owns
// 128x32 of BOTH h1,h3. 2-deep dbuf, 64 KB/tile (A 32K | B1 16K | B3 16K).
// 4 quadrant phases per K-tile: Q1=Alo*B1, Q2=Alo*B3, Q3=Ahi*B1, Q4=Ahi*B3.
// Reads 8/4/8/4 b128 per phase; B-frags held in regs across phases; B1 of the
// NEXT tile read at P4 (after its landed-guarantee). Stages: 2 GLDS/phase.
//
// Landed-guarantees (per-wave issue order: ...B3(k)@P4(k-1), A01(k+1)@P1,
// A23@P2, B1@P3, B3@P4):
//   P4(k-1): vmcnt(2)+BAR  => A01,A23,B1 of tile k landed  (B3(k) may fly)
//   P1(k):   vmcnt(2)+BAR  => B3(k) landed (before P2 reads it)
// Overwrite-safety: each stage targets a region whose last reads (tile k-1)
// were register-consumed before the previous collective barrier.
__global__ __launch_bounds__(512, 2) void gemm1_kernel(
    const bf16* __restrict__ X, const bf16* __restrict__ W1,
    const bf16* __restrict__ W3, const int* __restrict__ counts,
    bf16* __restrict__ Hb) {
  const int cb = blockIdx.x;   // NH/128 = 8
  const int rb = blockIdx.y;   // NT/256 = 64
  const int t = threadIdx.x;
  const int lane = t & 63;
  const int wave = t >> 6;
  const int wr = wave >> 2;    // 0..1 : 128 rows
  const int wc = wave & 3;     // 0..3 : 32 cols
  const int l16 = lane & 15;
  const int kq = lane >> 4;
  const int sx0 = ((0 + kq) ^ (l16 & 7)) * 8;   // ks=0 physical slot offset
  const int sx1 = ((4 + kq) ^ (l16 & 7)) * 8;   // ks=1

  const int row0 = rb * 256;
  const int e = expert_of_row(counts, row0);

  const bf16* Xe  = X  + (size_t)row0 * ND;
  const bf16* W1e = W1 + (size_t)e * NH * ND + (size_t)cb * 128 * ND;
  const bf16* W3e = W3 + (size_t)e * NH * ND + (size_t)cb * 128 * ND;

  __shared__ __align__(16) bf16 lds[2 * 32768];   // 128 KiB, 64 KB per buffer

  const int t8 = t * 8;
  const int srow8 = t >> 3;                         // 0..63
  const int scol8 = ((t & 7) ^ (srow8 & 7)) * 8;    // pre-swizzled global col
  const bf16* pA  = Xe  + (size_t)srow8 * ND + scol8;
  const bf16* pB1 = W1e + (size_t)srow8 * ND + scol8;
  const bf16* pB3 = W3e + (size_t)srow8 * ND + scol8;

  const int arow  = (wr * 128 + l16) * 64;            // A region base (elems)
  const int b1row = 16384 + (wc * 32 + l16) * 64;     // B1 region
  const int b3row = 24576 + (wc * 32 + l16) * 64;     // B3 region

  f32x4 acc1[8][2] = {};
  f32x4 acc3[8][2] = {};

  const int NK = ND / 64;   // 32

  // ---- prologue: stage tile 0 -> buf0; read B1(0) into regs ----
  GLDS16(pA,                     lds + t8);
  GLDS16(pA  + (size_t)64 * ND,  lds + 4096  + t8);
  GLDS16(pA  + (size_t)128 * ND, lds + 8192  + t8);
  GLDS16(pA  + (size_t)192 * ND, lds + 12288 + t8);
  GLDS16(pB1,                    lds + 16384 + t8);
  GLDS16(pB1 + (size_t)64 * ND,  lds + 20480 + t8);
  GLDS16(pB3,                    lds + 24576 + t8);
  GLDS16(pB3 + (size_t)64 * ND,  lds + 28672 + t8);
  WAIT_VM(0);
  BAR();

  bf16x8 b1h[2][2];
#pragma unroll
  for (int j = 0; j < 2; ++j) {
    b1h[j][0] = *(const bf16x8*)(lds + b1row + j * 1024 + sx0);
    b1h[j][1] = *(const bf16x8*)(lds + b1row + j * 1024 + sx1);
  }

  for (int kt = 0; kt < NK - 1; ++kt) {
    bf16* bufc = lds + (kt & 1) * 32768;
    bf16* nb   = lds + ((kt + 1) & 1) * 32768;
    const size_t ko1 = (size_t)(kt + 1) * 64;

    // ---- P1: read A-lo | stage A01(k+1) | vmcnt(2) [B3(k) landed] | Q1 ----
    bf16x8 alo[4][2];
#pragma unroll
    for (int i = 0; i < 4; ++i) {
      alo[i][0] = *(const bf16x8*)(bufc + arow + i * 1024 + sx0);
      alo[i][1] = *(const bf16x8*)(bufc + arow + i * 1024 + sx1);
    }
    GLDS16(pA + ko1,                   nb + t8);
    GLDS16(pA + (size_t)64 * ND + ko1, nb + 4096 + t8);
    WAIT_VM(2);
    BAR();
    __builtin_amdgcn_s_setprio(1);
#pragma unroll
    for (int i = 0; i < 4; ++i)
#pragma unroll
      for (int j = 0; j < 2; ++j) {
        acc1[i][j] = __builtin_amdgcn_mfma_f32_16x16x32_bf16(alo[i][0], b1h[j][0], acc1[i][j], 0, 0, 0);
        acc1[i][j] = __builtin_amdgcn_mfma_f32_16x16x32_bf16(alo[i][1], b1h[j][1], acc1[i][j], 0, 0, 0);
      }
    __builtin_amdgcn_s_setprio(0);

    // ---- P2: read B3(k) | stage A23(k+1) | Q2 ----
    bf16x8 b3h[2][2];
#pragma unroll
    for (int j = 0; j < 2; ++j) {
      b3h[j][0] = *(const bf16x8*)(bufc + b3row + j * 1024 + sx0);
      b3h[j][1] = *(const bf16x8*)(bufc + b3row + j * 1024 + sx1);
    }
    GLDS16(pA + (size_t)128 * ND + ko1, nb + 8192  + t8);
    GLDS16(pA + (size_t)192 * ND + ko1, nb + 12288 + t8);
    BAR();
    __builtin_amdgcn_s_setprio(1);
#pragma unroll
    for (int i = 0; i < 4; ++i)
#pragma unroll
      for (int j = 0; j < 2; ++j) {
        acc3[i][j] = __builtin_amdgcn_mfma_f32_16x16x32_bf16(alo[i][0], b3h[j][0], acc3[i][j], 0, 0, 0);
        acc3[i][j] = __builtin_amdgcn_mfma_f32_16x16x32_bf16(alo[i][1], b3h[j][1], acc3[i][j], 0, 0, 0);
      }
    __builtin_amdgcn_s_setprio(0);

    // ---- P3: read A-hi | stage B1(k+1) | Q3 ----
    bf16x8 ahi[4][2];
#pragma unroll
    for (int i = 0; i < 4; ++i) {
      ahi[i][0] = *(const bf16x8*)(bufc + arow + (4 + i) * 1024 + sx0);
      ahi[i][1] = *(const bf16x8*)(bufc + arow + (4 + i) * 1024 + sx1);
    }
    GLDS16(pB1 + ko1,                   nb + 16384 + t8);
    GLDS16(pB1 + (size_t)64 * ND + ko1, nb + 20480 + t8);
    BAR();
    __builtin_amdgcn_s_setprio(1);
#pragma unroll
    for (int i = 0; i < 4; ++i)
#pragma unroll
      for (int j = 0; j < 2; ++j) {
        acc1[4 + i][j] = __builtin_amdgcn_mfma_f32_16x16x32_bf16(ahi[i][0], b1h[j][0], acc1[4 + i][j], 0, 0, 0);
        acc1[4 + i][j] = __builtin_amdgcn_mfma_f32_16x16x32_bf16(ahi[i][1], b1h[j][1], acc1[4 + i][j], 0, 0, 0);
      }
    __builtin_amdgcn_s_setprio(0);

    // ---- P4: stage B3(k+1) | vmcnt(2) [A01,A23,B1(k+1) landed] | Q4 |
    //          read B1(k+1) from nb (post-MFMA, covered by this vmcnt+BAR) ----
    GLDS16(pB3 + ko1,                   nb + 24576 + t8);
    GLDS16(pB3 + (size_t)64 * ND + ko1, nb + 28672 + t8);
    WAIT_VM(2);
    BAR();
    __builtin_amdgcn_s_setprio(1);
#pragma unroll
    for (int i = 0; i < 4; ++i)
#pragma unroll
      for (int j = 0; j < 2; ++j) {
        acc3[4 + i][j] = __builtin_amdgcn_mfma_f32_16x16x32_bf16(ahi[i][0], b3h[j][0], acc3[4 + i][j], 0, 0, 0);
        acc3[4 + i][j] = __builtin_amdgcn_mfma_f32_16x16x32_bf16(ahi[i][1], b3h[j][1], acc3[4 + i][j], 0, 0, 0);
      }
    __builtin_amdgcn_s_setprio(0);
#pragma unroll
    for (int j = 0; j < 2; ++j) {
      b1h[j][0] = *(const bf16x8*)(nb + b1row + j * 1024 + sx0);
      b1h[j][1] = *(const bf16x8*)(nb + b1row + j * 1024 + sx1);
    }
  }

  // ---- final K-tile: no staging ----
  {
    bf16* bufc = lds + ((NK - 1) & 1) * 32768;
    bf16x8 alo[4][2], ahi[4][2], b3h[2][2];
#pragma unroll
    for (int i = 0; i < 4; ++i) {
      alo[i][0] = *(const bf16x8*)(bufc + arow + i * 1024 + sx0);
      alo[i][1] = *(const bf16x8*)(bufc + arow + i * 1024 + sx1);
    }
    WAIT_VM(0);   // drain B3(NK-1)
    BAR();
#pragma unroll
    for (int j = 0; j < 2; ++j) {
      b3h[j][0] = *(const bf16x8*)(bufc + b3row + j * 1024 + sx0);
      b3h[j][1] = *(const bf16x8*)(bufc + b3row + j * 1024 + sx1);
    }
#pragma unroll
    for (int i = 0; i < 4; ++i) {
      ahi[i][0] = *(const bf16x8*)(bufc + arow + (4 + i) * 1024 + sx0);
      ahi[i][1] = *(const bf16x8*)(bufc + arow + (4 + i) * 1024 + sx1);
    }
    __builtin_amdgcn_s_setprio(1);
#pragma unroll
    for (int i = 0; i < 4; ++i)
#pragma unroll
      for (int j = 0; j < 2; ++j) {
        acc1[i][j] = __builtin_amdgcn_mfma_f32_16x16x32_bf16(alo[i][0], b1h[j][0], acc1[i][j], 0, 0, 0);
        acc1[i][j] = __builtin_amdgcn_mfma_f32_16x16x32_bf16(alo[i][1], b1h[j][1], acc1[i][j], 0, 0, 0);
        acc3[i][j] = __builtin_amdgcn_mfma_f32_16x16x32_bf16(alo[i][0], b3h[j][0], acc3[i][j], 0, 0, 0);
        acc3[i][j] = __builtin_amdgcn_mfma_f32_16x16x32_bf16(alo[i][1], b3h[j][1], acc3[i][j], 0, 0, 0);
        acc1[4 + i][j] = __builtin_amdgcn_mfma_f32_16x16x32_bf16(ahi[i][0], b1h[j][0], acc1[4 + i][j], 0, 0, 0);
        acc1[4 + i][j] = __builtin_amdgcn_mfma_f32_16x16x32_bf16(ahi[i][1], b1h[j][1], acc1[4 + i][j], 0, 0, 0);
        acc3[4 + i][j] = __builtin_amdgcn_mfma_f32_16x16x32_bf16(ahi[i][0], b3h[j][0], acc3[4 + i][j], 0, 0, 0);
        acc3[4 + i][j] = __builtin_amdgcn_mfma_f32_16x16x32_bf16(ahi[i][1], b3h[j][1], acc3[4 + i][j], 0, 0, 0);
      }
    __builtin_amdgcn_s_setprio(0);
  }

  // Epilogue: C/D layout col=lane&15, row=(lane>>4)*4+reg. silu(a1)*a3 -> bf16.
  const int rbase = row0 + wr * 128 + kq * 4;
  const int cbase = cb * 128 + wc * 32 + l16;
#pragma unroll
  for (int i = 0; i < 8; ++i)
#pragma unroll
    for (int j = 0; j < 2; ++j) {
      const int col = cbase + j * 16;
#pragma unroll
      for (int r = 0; r < 4; ++r) {
        const int row = rbase + i * 16 + r;
        const float v1 = acc1[i][j][r];
        const float v3 = acc3[i][j][r];
        const float hv = (v1 / (1.0f + __expf(-v1))) * v3;
        Hb[(size_t)row * NH + col] = (bf16)hv;
      }
    }
}

// ---------------- GEMM2: out = h @ w2^T, f32 out ------------------------------
// BM=256, BN=256, BK=64. 8 waves (2x4); wave owns rows wr*128..+127 and the
// SPLIT column set {wc*32..+31} u {128+wc*32..+31} so its low-half B frags are
// staged in P3 and high-half in P4 (mirrors gemm1's guarantee schedule).
// Quads: Q1=Alo*BL, Q2=Alo*BH, Q3=Ahi*BL, Q4=Ahi*BH.
__global__ __launch_bounds__(512, 2) void gemm2_kernel(
    const bf16* __restrict__ Hb, const bf16* __restrict__ W2,
    const int* __restrict__ counts, float* __restrict__ Out) {
  const int cb = blockIdx.x;   // ND/256 = 8
  const int rb = blockIdx.y;   // NT/256 = 64
  const int t = threadIdx.x;
  const int lane = t & 63;
  const int wave = t >> 6;
  const int wr = wave >> 2;
  const int wc = wave & 3;
  const int l16 = lane & 15;
  const int kq = lane >> 4;
  const int sx0 = ((0 + kq) ^ (l16 & 7)) * 8;
  const int sx1 = ((4 + kq) ^ (l16 & 7)) * 8;

  const int row0 = rb * 256;
  const int e = expert_of_row(counts, row0);

  const bf16* He  = Hb + (size_t)row0 * NH;
  const bf16* W2e = W2 + (size_t)e * ND * NH + (size_t)cb * 256 * NH;

  __shared__ __align__(16) bf16 lds[2 * 32768];   // 128 KiB

  const int t8 = t * 8;
  const int srow8 = t >> 3;
  const int scol8 = ((t & 7) ^ (srow8 & 7)) * 8;
  const bf16* pA = He  + (size_t)srow8 * NH + scol8;
  const bf16* pB = W2e + (size_t)srow8 * NH + scol8;

  const int arow  = (wr * 128 + l16) * 64;
  const int blrow = 16384 + (wc * 32 + l16) * 64;          // B rows 0..127
  const int bhrow = 16384 + (128 + wc * 32 + l16) * 64;    // B rows 128..255

  f32x4 acc[8][4] = {};   // [m-frag][ j0,j1 = low cols ; j2,j3 = high cols ]

  const int NK = NH / 64;   // 16

  // ---- prologue ----
  GLDS16(pA,                     lds + t8);
  GLDS16(pA + (size_t)64 * NH,   lds + 4096  + t8);
  GLDS16(pA + (size_t)128 * NH,  lds + 8192  + t8);
  GLDS16(pA + (size_t)192 * NH,  lds + 12288 + t8);
  GLDS16(pB,                     lds + 16384 + t8);
  GLDS16(pB + (size_t)64 * NH,   lds + 20480 + t8);
  GLDS16(pB + (size_t)128 * NH,  lds + 24576 + t8);
  GLDS16(pB + (size_t)192 * NH,  lds + 28672 + t8);
  WAIT_VM(0);
  BAR();

  bf16x8 blh[2][2];
#pragma unroll
  for (int j = 0; j < 2; ++j) {
    blh[j][0] = *(const bf16x8*)(lds + blrow + j * 1024 + sx0);
    blh[j][1] = *(const bf16x8*)(lds + blrow + j * 1024 + sx1);
  }

  for (int kt = 0; kt < NK - 1; ++kt) {
    bf16* bufc = lds + (kt & 1) * 32768;
    bf16* nb   = lds + ((kt + 1) & 1) * 32768;
    const size_t ko1 = (size_t)(kt + 1) * 64;

    // ---- P1: read A-lo | stage A01(k+1) | vmcnt(2) [BH(k) landed] | Q1 ----
    bf16x8 alo[4][2];
#pragma unroll
    for (int i = 0; i < 4; ++i) {
      alo[i][0] = *(const bf16x8*)(bufc + arow + i * 1024 + sx0);
      alo[i][1] = *(const bf16x8*)(bufc + arow + i * 1024 + sx1);
    }
    GLDS16(pA + ko1,                   nb + t8);
    GLDS16(pA + (size_t)64 * NH + ko1, nb + 4096 + t8);
    WAIT_VM(2);
    BAR();
    __builtin_amdgcn_s_setprio(1);
#pragma unroll
    for (int i = 0; i < 4; ++i)
#pragma unroll
      for (int j = 0; j < 2; ++j) {
        acc[i][j] = __builtin_amdgcn_mfma_f32_16x16x32_bf16(alo[i][0], blh[j][0], acc[i][j], 0, 0, 0);
        acc[i][j] = __builtin_amdgcn_mfma_f32_16x16x32_bf16(alo[i][1], blh[j][1], acc[i][j], 0, 0, 0);
      }
    __builtin_amdgcn_s_setprio(0);

    // ---- P2: read BH(k) | stage A23(k+1) | Q2 ----
    bf16x8 bhh[2][2];
#pragma unroll
    for (int j = 0; j < 2; ++j) {
      bhh[j][0] = *(const bf16x8*)(bufc + bhrow + j * 1024 + sx0);
      bhh[j][1] = *(const bf16x8*)(bufc + bhrow + j * 1024 + sx1);
    }
    GLDS16(pA + (size_t)128 * NH + ko1, nb + 8192  + t8);
    GLDS16(pA + (size_t)192 * NH + ko1, nb + 12288 + t8);
    BAR();
    __builtin_amdgcn_s_setprio(1);
#pragma unroll
    for (int i = 0; i < 4; ++i)
#pragma unroll
      for (int j = 0; j < 2; ++j) {
        acc[i][2 + j] = __builtin_amdgcn_mfma_f32_16x16x32_bf16(alo[i][0], bhh[j][0], acc[i][2 + j], 0, 0, 0);
        acc[i][2 + j] = __builtin_amdgcn_mfma_f32_16x16x32_bf16(alo[i][1], bhh[j][1], acc[i][2 + j], 0, 0, 0);
      }
    __builtin_amdgcn_s_setprio(0);

    // ---- P3: read A-hi | stage BL(k+1) | Q3 ----
    bf16x8 ahi[4][2];
#pragma unroll
    for (int i = 0; i < 4; ++i) {
      ahi[i][0] = *(const bf16x8*)(bufc + arow + (4 + i) * 1024 + sx0);
      ahi[i][1] = *(const bf16x8*)(bufc + arow + (4 + i) * 1024 + sx1);
    }
    GLDS16(pB + ko1,                   nb + 16384 + t8);
    GLDS16(pB + (size_t)64 * NH + ko1, nb + 20480 + t8);
    BAR();
    __builtin_amdgcn_s_setprio(1);
#pragma unroll
    for (int i = 0; i < 4; ++i)
#pragma unroll
      for (int j = 0; j < 2; ++j) {
        acc[4 + i][j] = __builtin_amdgcn_mfma_f32_16x16x32_bf16(ahi[i][0], blh[j][0], acc[4 + i][j], 0, 0, 0);
        acc[4 + i][j] = __builtin_amdgcn_mfma_f32_16x16x32_bf16(ahi[i][1], blh[j][1], acc[4 + i][j], 0, 0, 0);
      }
    __builtin_amdgcn_s_setprio(0);

    // ---- P4: stage BH(k+1) | vmcnt(2) | Q4 | read BL(k+1) ----
    GLDS16(pB + (size_t)128 * NH + ko1, nb + 24576 + t8);
    GLDS16(pB + (size_t)192 * NH + ko1, nb + 28672 + t8);
    WAIT_VM(2);
    BAR();
    __builtin_amdgcn_s_setprio(1);
#pragma unroll
    for (int i = 0; i < 4; ++i)
#pragma unroll
      for (int j = 0; j < 2; ++j) {
        acc[4 + i][2 + j] = __builtin_amdgcn_mfma_f32_16x16x32_bf16(ahi[i][0], bhh[j][0], acc[4 + i][2 + j], 0, 0, 0);
        acc[4 + i][2 + j] = __builtin_amdgcn_mfma_f32_16x16x32_bf16(ahi[i][1], bhh[j][1], acc[4 + i][2 + j], 0, 0, 0);
      }
    __builtin_amdgcn_s_setprio(0);
#pragma unroll
    for (int j = 0; j < 2; ++j) {
      blh[j][0] = *(const bf16x8*)(nb + blrow + j * 1024 + sx0);
      blh[j][1] = *(const bf16x8*)(nb + blrow + j * 1024 + sx1);
    }
  }

  // ---- final K-tile ----
  {
    bf16* bufc = lds + ((NK - 1) & 1) * 32768;
    bf16x8 alo[4][2], ahi[4][2], bhh[2][2];
#pragma unroll
    for (int i = 0; i < 4; ++i) {
      alo[i][0] = *(const bf16x8*)(bufc + arow + i * 1024 + sx0);
      alo[i][1] = *(const bf16x8*)(bufc + arow + i * 1024 + sx1);
    }
    WAIT_VM(0);   // drain BH(NK-1)
    BAR();
#pragma unroll
    for (int j = 0; j < 2; ++j) {
      bhh[j][0] = *(const bf16x8*)(bufc + bhrow + j * 1024 + sx0);
      bhh[j][1] = *(const bf16x8*)(bufc + bhrow + j * 1024 + sx1);
    }
#pragma unroll
    for (int i = 0; i < 4; ++i) {
      ahi[i][0] = *(const bf16x8*)(bufc + arow + (4 + i) * 1024 + sx0);
      ahi[i][1] = *(const bf16x8*)(bufc + arow + (4 + i) * 1024 + sx1);
    }
    __builtin_amdgcn_s_setprio(1);
#pragma unroll
    for (int i = 0; i < 4; ++i)
#pragma unroll
      for (int j = 0; j < 2; ++j) {
        acc[i][j] = __builtin_amdgcn_mfma_f32_16x16x32_bf16(alo[i][0], blh[j][0], acc[i][j], 0, 0, 0);
        acc[i][j] = __builtin_amdgcn_mfma_f32_16x16x32_bf16(alo[i][1], blh[j][1], acc[i][j], 0, 0, 0);
        acc[i][2 + j] = __builtin_amdgcn_mfma_f32_16x16x32_bf16(alo[i][0], bhh[j][0], acc[i][2 + j], 0, 0, 0);
        acc[i][2 + j] = __builtin_amdgcn_mfma_f32_16x16x32_bf16(alo[i][1], bhh[j][1], acc[i][2 + j], 0, 0, 0);
        acc[4 + i][j] = __builtin_amdgcn_mfma_f32_16x16x32_bf16(ahi[i][0], blh[j][0], acc[4 + i][j], 0, 0, 0);
        acc[4 + i][j] = __builtin_amdgcn_mfma_f32_16x16x32_bf16(ahi[i][1], blh[j][1], acc[4 + i][j], 0, 0, 0);
        acc[4 + i][2 + j] = __builtin_amdgcn_mfma_f32_16x16x32_bf16(ahi[i][0], bhh[j][0], acc[4 + i][2 + j], 0, 0, 0);
        acc[4 + i][2 + j] = __builtin_amdgcn_mfma_f32_16x16x32_bf16(ahi[i][1], bhh[j][1], acc[4 + i][2 + j], 0, 0, 0);
      }
    __builtin_amdgcn_s_setprio(0);
  }

  // Epilogue: split column set: j<2 -> cols cb*256+wc*32+j*16 ; j>=2 -> +128.
  const int rbase = row0 + wr * 128 + kq * 4;
  const int cl = cb * 256 + wc * 32 + l16;
#pragma unroll
  for (int i = 0; i < 8; ++i)
#pragma unroll
    for (int j = 0; j < 4; ++j) {
      const int col = cl + (j & 1) * 16 + (j >> 1) * 128;
#pragma unroll
      for (int r = 0; r < 4; ++r) {
        const int row = rbase + i * 16 + r;
        Out[(size_t)row * ND + col] = acc[i][(j >> 1) * 2 + (j & 1)][r];
      }
    }
}

// -----------------------------------------------------------------------------
extern "C" void kernel_launch(void* const* d_in, const int* in_sizes, int n_in,
                              void* d_out, int out_size, void* d_ws, size_t ws_size,
                              hipStream_t stream) {
  const float* x     = (const float*)d_in[0];
  const int* counts  = (const int*)d_in[1];
  const float* w1    = (const float*)d_in[2];
  const float* w2    = (const float*)d_in[3];
  const float* w3    = (const float*)d_in[4];
  float* out = (float*)d_out;

  char* ws = (char*)d_ws;
  const size_t xN = (size_t)NT * ND;       // 33.5M elems
  const size_t wN = (size_t)NE * NH * ND;  // 16.8M elems per weight
  bf16* xb  = (bf16*)ws;                                  //  64 MiB
  bf16* w1b = (bf16*)(ws + xN * 2);                       // +32 MiB
  bf16* w3b = (bf16*)(ws + xN * 2 + wN * 2);              // +32 MiB
  bf16* w2b = (bf16*)(ws + xN * 2 + 2 * wN * 2);          // +32 MiB
  bf16* hb  = (bf16*)(ws + xN * 2 + 3 * wN * 2);          // +32 MiB (h: T x H bf16)

  { int n8 = (int)(xN / 8); cvt_kernel<<<dim3((n8 + 255) / 256), dim3(256), 0, stream>>>(x, xb, n8); }
  { int n8 = (int)(wN / 8); cvt_kernel<<<dim3((n8 + 255) / 256), dim3(256), 0, stream>>>(w1, w1b, n8); }
  { int n8 = (int)(wN / 8); cvt_kernel<<<dim3((n8 + 255) / 256), dim3(256), 0, stream>>>(w3, w3b, n8); }
  { int n8 = (int)(wN / 8); cvt_kernel<<<dim3((n8 + 255) / 256), dim3(256), 0, stream>>>(w2, w2b, n8); }

  gemm1_kernel<<<dim3(NH / 128, NT / 256), dim3(512), 0, stream>>>(xb, w1b, w3b, counts, hb);
  gemm2_kernel<<<dim3(ND / 256, NT / 256), dim3(512), 0, stream>>>(hb, w2b, counts, out);
}